// Round 1
// 2067.753 us; speedup vs baseline: 1.1652x; 1.1652x over previous
//
#include <hip/hip_runtime.h>

#define NA 50000
#define NE 1600000
#define HH 128
#define D1 129
#define EPS 1e-3f

typedef __bf16 bf16_t;
typedef bf16_t bf16x8 __attribute__((ext_vector_type(8)));
typedef bf16_t bf16x4 __attribute__((ext_vector_type(4)));
typedef float f32x4 __attribute__((ext_vector_type(4)));

// ---- workspace layout (float offsets) ----
#define OFF_A1   0
#define OFF_C1   129
#define OFF_A2   258
#define OFF_C2   387
#define OFF_WEFF 516
#define OFF_DVEC (OFF_WEFF + 384*129)          // 50052
#define OFF_Q1   (OFF_DVEC + 129)              // 50181
#define OFF_Q2   (OFF_Q1 + 128*128)
#define OFF_q1   (OFF_Q2 + 128*128)
#define OFF_q2   (OFF_q1 + 128)
#define OFF_QF   (OFF_q2 + 128)
#define OFF_qf   (OFF_QF + 128*128)
#define OFF_WMT  (((OFF_qf + 128) + 3) & ~3)   // WmidT bf16 [144][128] -> 9216 floats
#define OFF_WTT  (OFF_WMT + 9216)              // WtopT bf16 [144][128]
#define OFF_WBT  (OFF_WTT + 9216)              // WbotT bf16 [144][128]
#define OFF_QFT  (OFF_WBT + 9216)              // QfT  bf16 [128][128] -> 8192 floats
#define OFF_PI   (OFF_QFT + 8192)
#define OFF_PJ   (OFF_PI + NA*D1)
#define OFF_ACC  (OFF_PJ + NA*D1)
#define OFF_ACC2 (OFF_ACC + NA*HH)
// CSR scratch (ints stored in float slots)
#define OFF_CNT  (OFF_ACC2 + NA)               // int cnt[NA]   (zeroed by the big memset)
#define OFF_CUR  (OFF_CNT + NA)                // int cursor[NA]
#define OFF_EDG  (OFF_CUR + NA)                // int edge_of[NE]
// total = OFF_EDG + NE ~= 21.2M floats ~= 85 MB

// ---------------- setup kernels (tiny) ----------------
__global__ void k_affine(const float* __restrict__ g1, const float* __restrict__ b1,
                         const float* __restrict__ m1, const float* __restrict__ v1,
                         const float* __restrict__ g2, const float* __restrict__ b2,
                         const float* __restrict__ m2, const float* __restrict__ v2,
                         float* __restrict__ ws) {
    for (int idx = threadIdx.x; idx < 2 * D1; idx += blockDim.x) {
        if (idx < D1) {
            float a = g1[idx] * rsqrtf(v1[idx] + EPS);
            ws[OFF_A1 + idx] = a;
            ws[OFF_C1 + idx] = b1[idx] - m1[idx] * a;
        } else {
            int n = idx - D1;
            float a = g2[n] * rsqrtf(v2[n] + EPS);
            ws[OFF_A2 + n] = a;
            ws[OFF_C2 + n] = b2[n] - m2[n] * a;
        }
    }
}

__global__ void k_weff(const float* __restrict__ W1, const float* __restrict__ W2,
                       float* __restrict__ ws) {
    int idx = blockIdx.x * blockDim.x + threadIdx.x;
    if (idx >= 384 * D1 + D1) return;
    const float* a1 = ws + OFF_A1;
    const float* c1 = ws + OFF_C1;
    const float* a2 = ws + OFF_A2;
    const float* c2 = ws + OFF_C2;
    if (idx < 384 * D1) {
        int k = idx / D1, n = idx % D1;
        float s = 0.f;
        for (int t = 0; t < D1; ++t)
            s += W1[(size_t)k * D1 + t] * a1[t] * W2[(size_t)t * D1 + n];
        ws[OFF_WEFF + idx] = s * a2[n];
    } else {
        int n = idx - 384 * D1;
        float s = 0.f;
        for (int t = 0; t < D1; ++t)
            s += c1[t] * W2[(size_t)t * D1 + n];
        ws[OFF_DVEC + n] = s * a2[n] + c2[n];
    }
}

__global__ void k_resid(const float* __restrict__ r1w1, const float* __restrict__ r1b1,
                        const float* __restrict__ r1w2, const float* __restrict__ r1b2,
                        const float* __restrict__ r2w1, const float* __restrict__ r2b1,
                        const float* __restrict__ r2w2, const float* __restrict__ r2b2,
                        float* __restrict__ ws) {
    int idx = blockIdx.x * blockDim.x + threadIdx.x;
    if (idx >= 2 * (128 * 128 + 128)) return;
    int layer = idx / (128 * 128 + 128);
    int r = idx % (128 * 128 + 128);
    const float* w1 = layer ? r2w1 : r1w1;
    const float* b1 = layer ? r2b1 : r1b1;
    const float* w2 = layer ? r2w2 : r1w2;
    const float* b2 = layer ? r2b2 : r1b2;
    float* Q = ws + (layer ? OFF_Q2 : OFF_Q1);
    float* q = ws + (layer ? OFF_q2 : OFF_q1);
    if (r < 128 * 128) {
        int i = r >> 7, j = r & 127;
        float s = (i == j) ? 1.f : 0.f;
        for (int t = 0; t < 128; ++t)
            s += w1[i * 128 + t] * w2[t * 128 + j];
        Q[r] = s;
    } else {
        int j = r - 128 * 128;
        float s = b2[j];
        for (int t = 0; t < 128; ++t)
            s += b1[t] * w2[t * 128 + j];
        q[j] = s;
    }
}

__global__ void k_qf(float* __restrict__ ws) {
    int idx = blockIdx.x * blockDim.x + threadIdx.x;
    if (idx >= 128 * 128 + 128) return;
    const float* Q1 = ws + OFF_Q1;
    const float* Q2 = ws + OFF_Q2;
    if (idx < 128 * 128) {
        int i = idx >> 7, j = idx & 127;
        float s = 0.f;
        for (int m = 0; m < 128; ++m)
            s += Q1[i * 128 + m] * Q2[m * 128 + j];
        ws[OFF_QF + idx] = s;
    } else {
        int j = idx - 128 * 128;
        const float* q1 = ws + OFF_q1;
        float s = ws[OFF_q2 + j];
        for (int m = 0; m < 128; ++m)
            s += q1[m] * Q2[m * 128 + j];
        ws[OFF_qf + j] = s;
    }
}

// pack transposed bf16 weights: WmidT/WtopT/WbotT [144][128], QfT [128][128]
__global__ void k_pack(float* __restrict__ ws) {
    int idx = blockIdx.x * blockDim.x + threadIdx.x;
    const float* Weff = ws + OFF_WEFF;
    if (idx < 18432) {
        int n = idx >> 7, k = idx & 127;
        float v = (n < 128) ? Weff[(size_t)(128 + k) * D1 + n + 1]
                            : ((n == 128) ? Weff[(size_t)(128 + k) * D1] : 0.f);
        ((bf16_t*)(ws + OFF_WMT))[idx] = (bf16_t)v;
    } else if (idx < 2 * 18432) {
        int r = idx - 18432;
        int n = r >> 7, k = r & 127;
        float v = (n < D1) ? Weff[(size_t)k * D1 + n] : 0.f;
        ((bf16_t*)(ws + OFF_WTT))[r] = (bf16_t)v;
    } else if (idx < 3 * 18432) {
        int r = idx - 2 * 18432;
        int n = r >> 7, k = r & 127;
        float v = (n < D1) ? Weff[(size_t)(256 + k) * D1 + n] : 0.f;
        ((bf16_t*)(ws + OFF_WBT))[r] = (bf16_t)v;
    } else if (idx < 3 * 18432 + 16384) {
        int r = idx - 3 * 18432;
        int n = r >> 7, k = r & 127;
        ((bf16_t*)(ws + OFF_QFT))[r] = (bf16_t)ws[OFF_QF + k * 128 + n];
    }
}

// ---------------- CSR build: histogram -> scan -> scatter ----------------
__global__ void k_hist(const int* __restrict__ idx_i, float* __restrict__ ws) {
    int e = blockIdx.x * blockDim.x + threadIdx.x;
    if (e < NE) atomicAdd((int*)(ws + OFF_CNT) + idx_i[e], 1);
}

__global__ void k_scan(float* __restrict__ ws) {
    const int* cnt = (const int*)(ws + OFF_CNT);
    int* cursor = (int*)(ws + OFF_CUR);
    __shared__ int ps[1024];
    int t = threadIdx.x;
    const int CH = (NA + 1023) / 1024;  // 49
    int base = t * CH;
    int s = 0;
    for (int k = 0; k < CH; ++k) {
        int i = base + k;
        if (i < NA) s += cnt[i];
    }
    ps[t] = s;
    __syncthreads();
    for (int off = 1; off < 1024; off <<= 1) {
        int v = (t >= off) ? ps[t - off] : 0;
        __syncthreads();
        ps[t] += v;
        __syncthreads();
    }
    int run = t ? ps[t - 1] : 0;
    for (int k = 0; k < CH; ++k) {
        int i = base + k;
        if (i < NA) { cursor[i] = run; run += cnt[i]; }
    }
}

__global__ void k_scatter(const int* __restrict__ idx_i, float* __restrict__ ws) {
    int e = blockIdx.x * blockDim.x + threadIdx.x;
    if (e < NE) {
        int i = idx_i[e];
        int p = atomicAdd((int*)(ws + OFF_CUR) + i, 1);
        ((int*)(ws + OFF_EDG))[p] = e;
    }
}

// ---------------- MFMA dense GEMM: C[M][N] = (A + A2 + acc2*Pi') @ Wt^T + bias ----------------
__global__ __launch_bounds__(256) void k_gemm_mfma(
    const float* __restrict__ A, const float* __restrict__ A2,
    const float* __restrict__ Pi, const float* __restrict__ acc2,
    const bf16_t* __restrict__ Wt, const float* __restrict__ bias,
    float* __restrict__ C, int ldc, int N, int ntiles, int M) {
    __shared__ __align__(16) bf16_t As[64][136];
    int t = threadIdx.x;
    int m0 = blockIdx.x * 64;
#pragma unroll
    for (int it = 0; it < 8; ++it) {
        int idx = t + 256 * it;
        int r = idx >> 5, c4 = idx & 31;
        int grow = m0 + r;
        float4 v = make_float4(0.f, 0.f, 0.f, 0.f);
        if (grow < M) {
            v = ((const float4*)(A + (size_t)grow * 128))[c4];
            if (A2) {
                float4 w = ((const float4*)(A2 + (size_t)grow * 128))[c4];
                v.x += w.x; v.y += w.y; v.z += w.z; v.w += w.w;
            }
            if (acc2) {
                float s = acc2[grow];
                const float* p = Pi + (size_t)grow * D1 + 1 + c4 * 4;
                v.x += s * p[0]; v.y += s * p[1]; v.z += s * p[2]; v.w += s * p[3];
            }
        }
        bf16x4 tmp;
        tmp[0] = (bf16_t)v.x; tmp[1] = (bf16_t)v.y; tmp[2] = (bf16_t)v.z; tmp[3] = (bf16_t)v.w;
        *(bf16x4*)&As[r][c4 * 4] = tmp;
    }
    __syncthreads();
    int lane = t & 63, w = t >> 6;
    int ll = lane & 15, quad = lane >> 4;
    bf16x8 a[4];
#pragma unroll
    for (int k = 0; k < 4; ++k)
        a[k] = *(const bf16x8*)&As[w * 16 + ll][k * 32 + quad * 8];
    for (int nt = 0; nt < ntiles; ++nt) {
        const bf16_t* bp = Wt + (size_t)(nt * 16 + ll) * 128 + quad * 8;
        f32x4 acc = {0.f, 0.f, 0.f, 0.f};
#pragma unroll
        for (int k = 0; k < 4; ++k) {
            bf16x8 b = *(const bf16x8*)(bp + k * 32);
            acc = __builtin_amdgcn_mfma_f32_16x16x32_bf16(a[k], b, acc, 0, 0, 0);
        }
        int col = nt * 16 + ll;
        if (col < N) {
            float bv = bias ? bias[col] : 0.f;
#pragma unroll
            for (int r = 0; r < 4; ++r) {
                int row = m0 + w * 16 + quad * 4 + r;
                if (row < M) C[(size_t)row * ldc + col] = acc[r] + bv;
            }
        }
    }
}

// ---------------- edge kernel (destination-sorted): y2 = bond@Wmid + Pi[i] + Pj[j];
// msg = y2[0]*y2[1:]; in-LDS segmented reduction -> few coalesced atomics ----------------
__global__ __launch_bounds__(256) void k_edge_mfma(
    const float* __restrict__ bond, const int* __restrict__ idx_i,
    const int* __restrict__ idx_j, const int* __restrict__ edge_of,
    const bf16_t* __restrict__ WmidT,
    const float* __restrict__ Pi, const float* __restrict__ Pj,
    float* __restrict__ accb, float* __restrict__ acc2) {
    // union: staging As bf16[64][136] (17408 B)  /  message tile f32[64][132] (33792 B)
    __shared__ __align__(16) char smem[64 * 132 * 4];
    __shared__ int e_s[64], ii_s[64], jj_s[64];
    __shared__ float g_s[64];
    bf16_t (*As)[136] = (bf16_t(*)[136])smem;
    float (*ML)[132] = (float(*)[132])smem;

    int t = threadIdx.x;
    size_t p0 = (size_t)blockIdx.x * 64;
    if (t < 64) {
        int e = edge_of[p0 + t];
        e_s[t] = e;
        ii_s[t] = idx_i[e];
        jj_s[t] = idx_j[e];
    }
    __syncthreads();
#pragma unroll
    for (int it = 0; it < 8; ++it) {
        int idx = t + 256 * it;
        int r = idx >> 5, c4 = idx & 31;
        float4 v = ((const float4*)(bond + (size_t)e_s[r] * 128))[c4];
        bf16x4 tmp;
        tmp[0] = (bf16_t)v.x; tmp[1] = (bf16_t)v.y; tmp[2] = (bf16_t)v.z; tmp[3] = (bf16_t)v.w;
        *(bf16x4*)&As[r][c4 * 4] = tmp;
    }
    __syncthreads();
    int lane = t & 63, w = t >> 6;
    int ll = lane & 15, quad = lane >> 4;
    bf16x8 a[4];
#pragma unroll
    for (int k = 0; k < 4; ++k)
        a[k] = *(const bf16x8*)&As[w * 16 + ll][k * 32 + quad * 8];

    int ii[4], jj[4];
#pragma unroll
    for (int r = 0; r < 4; ++r) {
        int e = w * 16 + quad * 4 + r;
        ii[r] = ii_s[e];
        jj[r] = jj_s[e];
    }
    __syncthreads();  // As is dead from here; smem becomes ML

    // gate tile (WmidT rows 128..143; row 128 = gate column, rest zero)
    f32x4 ag = {0.f, 0.f, 0.f, 0.f};
    {
        const bf16_t* bp = WmidT + (size_t)(128 + ll) * 128 + quad * 8;
#pragma unroll
        for (int k = 0; k < 4; ++k) {
            bf16x8 b = *(const bf16x8*)(bp + k * 32);
            ag = __builtin_amdgcn_mfma_f32_16x16x32_bf16(a[k], b, ag, 0, 0, 0);
        }
    }
    float g[4];
    int src = lane & 48;  // lane quad*16 holds the gate (col 0 of the tile)
#pragma unroll
    for (int r = 0; r < 4; ++r) {
        float v = ag[r];
        if (ll == 0) v += Pi[(size_t)ii[r] * D1] + Pj[(size_t)jj[r] * D1];
        g[r] = __shfl(v, src);
    }
    if (ll == 0) {
#pragma unroll
        for (int r = 0; r < 4; ++r) g_s[w * 16 + quad * 4 + r] = g[r];
    }

    const float* pjb[4];
#pragma unroll
    for (int r = 0; r < 4; ++r) pjb[r] = Pj + (size_t)jj[r] * D1 + 1;

    for (int nt = 0; nt < 8; ++nt) {
        const bf16_t* bp = WmidT + (size_t)(nt * 16 + ll) * 128 + quad * 8;
        f32x4 acc = {0.f, 0.f, 0.f, 0.f};
#pragma unroll
        for (int k = 0; k < 4; ++k) {
            bf16x8 b = *(const bf16x8*)(bp + k * 32);
            acc = __builtin_amdgcn_mfma_f32_16x16x32_bf16(a[k], b, acc, 0, 0, 0);
        }
        int n = nt * 16 + ll;
#pragma unroll
        for (int r = 0; r < 4; ++r) {
            float y = acc[r] + pjb[r][n];
            ML[w * 16 + quad * 4 + r][n] = g[r] * y;
        }
    }
    __syncthreads();

    // segmented reduction over sorted rows: runs of equal atom flush once,
    // wave-uniform branches, 64-lane contiguous atomic bursts
    {
        int col = t & 127, half = t >> 7;
        int rb = half * 32;
        int cur = ii_s[rb];
        float s = 0.f;
        for (int r = rb; r < rb + 32; ++r) {
            int i = ii_s[r];
            if (i != cur) {
                atomicAdd(&accb[(size_t)cur * 128 + col], s);
                cur = i;
                s = 0.f;
            }
            s += ML[r][col];
        }
        atomicAdd(&accb[(size_t)cur * 128 + col], s);
    }
    // gate accumulation (2 threads walk 32 rows each)
    if (t < 2) {
        int rb = t * 32;
        int cur = ii_s[rb];
        float s = 0.f;
        for (int r = rb; r < rb + 32; ++r) {
            int i = ii_s[r];
            if (i != cur) {
                atomicAdd(&acc2[cur], s);
                cur = i;
                s = 0.f;
            }
            s += g_s[r];
        }
        atomicAdd(&acc2[cur], s);
    }
}

extern "C" void kernel_launch(void* const* d_in, const int* in_sizes, int n_in,
                              void* d_out, int out_size, void* d_ws, size_t ws_size,
                              hipStream_t stream) {
    const float* atom = (const float*)d_in[0];
    const float* bond = (const float*)d_in[1];
    const int* idx_i = (const int*)d_in[2];
    const int* idx_j = (const int*)d_in[3];
    const float* W1 = (const float*)d_in[4];
    const float* g1 = (const float*)d_in[5];
    const float* b1 = (const float*)d_in[6];
    const float* m1 = (const float*)d_in[7];
    const float* v1 = (const float*)d_in[8];
    const float* W2 = (const float*)d_in[9];
    const float* g2 = (const float*)d_in[10];
    const float* b2 = (const float*)d_in[11];
    const float* m2 = (const float*)d_in[12];
    const float* v2 = (const float*)d_in[13];
    const float* r1w1 = (const float*)d_in[14];
    const float* r1b1 = (const float*)d_in[15];
    const float* r1w2 = (const float*)d_in[16];
    const float* r1b2 = (const float*)d_in[17];
    const float* r2w1 = (const float*)d_in[18];
    const float* r2b1 = (const float*)d_in[19];
    const float* r2w2 = (const float*)d_in[20];
    const float* r2b2 = (const float*)d_in[21];
    float* ws = (float*)d_ws;
    float* out = (float*)d_out;

    // zero ACC + ACC2 + CNT (contiguous) up front
    hipMemsetAsync(ws + OFF_ACC, 0, (size_t)(NA * HH + 2 * NA) * sizeof(float), stream);

    // CSR build (independent of weight prep)
    k_hist<<<(NE + 255) / 256, 256, 0, stream>>>(idx_i, ws);
    k_scan<<<1, 1024, 0, stream>>>(ws);
    k_scatter<<<(NE + 255) / 256, 256, 0, stream>>>(idx_i, ws);

    k_affine<<<1, 256, 0, stream>>>(g1, b1, m1, v1, g2, b2, m2, v2, ws);
    k_weff<<<(384 * D1 + D1 + 255) / 256, 256, 0, stream>>>(W1, W2, ws);
    k_resid<<<(2 * (128 * 128 + 128) + 255) / 256, 256, 0, stream>>>(
        r1w1, r1b1, r1w2, r1b2, r2w1, r2b1, r2w2, r2b2, ws);
    k_qf<<<(128 * 128 + 128 + 255) / 256, 256, 0, stream>>>(ws);
    k_pack<<<(3 * 18432 + 16384 + 255) / 256, 256, 0, stream>>>(ws);

    // Pi = atom @ Wtop + dvec ; Pj = atom @ Wbot   (N=129)
    int gblocks = (NA + 63) / 64;
    k_gemm_mfma<<<gblocks, 256, 0, stream>>>(
        atom, nullptr, nullptr, nullptr, (const bf16_t*)(ws + OFF_WTT),
        ws + OFF_DVEC, ws + OFF_PI, D1, D1, 9, NA);
    k_gemm_mfma<<<gblocks, 256, 0, stream>>>(
        atom, nullptr, nullptr, nullptr, (const bf16_t*)(ws + OFF_WBT),
        nullptr, ws + OFF_PJ, D1, D1, 9, NA);

    k_edge_mfma<<<NE / 64, 256, 0, stream>>>(
        bond, idx_i, idx_j, (const int*)(ws + OFF_EDG), (const bf16_t*)(ws + OFF_WMT),
        ws + OFF_PI, ws + OFF_PJ, ws + OFF_ACC, ws + OFF_ACC2);

    // out = (atom + acc + acc2*Pi') @ Qf + qf
    k_gemm_mfma<<<gblocks, 256, 0, stream>>>(
        atom, ws + OFF_ACC, ws + OFF_PI, ws + OFF_ACC2, (const bf16_t*)(ws + OFF_QFT),
        ws + OFF_qf, out, 128, 128, 8, NA);
}

// Round 2
// 1830.710 us; speedup vs baseline: 1.3161x; 1.1295x over previous
//
#include <hip/hip_runtime.h>

#define NA 50000
#define NE 1600000
#define HH 128
#define D1 129
#define EPS 1e-3f

typedef __bf16 bf16_t;
typedef bf16_t bf16x8 __attribute__((ext_vector_type(8)));
typedef bf16_t bf16x4 __attribute__((ext_vector_type(4)));
typedef float f32x4 __attribute__((ext_vector_type(4)));

// ---- workspace layout (float offsets) ----
#define OFF_A1   0
#define OFF_C1   129
#define OFF_A2   258
#define OFF_C2   387
#define OFF_WEFF 516
#define OFF_DVEC (OFF_WEFF + 384*129)          // 50052
#define OFF_Q1   (OFF_DVEC + 129)              // 50181
#define OFF_Q2   (OFF_Q1 + 128*128)
#define OFF_q1   (OFF_Q2 + 128*128)
#define OFF_q2   (OFF_q1 + 128)
#define OFF_QF   (OFF_q2 + 128)
#define OFF_qf   (OFF_QF + 128*128)
#define OFF_WMT  (((OFF_qf + 128) + 3) & ~3)   // WmidT bf16 [144][128] -> 9216 floats
#define OFF_WTT  (OFF_WMT + 9216)              // WtopT bf16 [144][128]
#define OFF_WBT  (OFF_WTT + 9216)              // WbotT bf16 [144][128]
#define OFF_QFT  (OFF_WBT + 9216)              // QfT  bf16 [128][128] -> 8192 floats
#define OFF_PI   (OFF_QFT + 8192)
#define OFF_PJ   (OFF_PI + NA*D1)
#define OFF_ACC  (OFF_PJ + NA*D1)
#define OFF_ACC2 (OFF_ACC + NA*HH)
// CSR scratch (ints stored in float slots)
#define OFF_CNT  (OFF_ACC2 + NA)               // int cnt[NA]   (zeroed by the big memset)
#define OFF_CUR  (OFF_CNT + NA)                // int cursor[NA]
#define OFF_EDG  (OFF_CUR + NA)                // int edge_of[NE]
#define OFF_PART (OFF_EDG + NE)                // int partial sums for scan (256)
#define SCAN_NB  ((NA + 255) / 256)            // 196

// ---------------- setup kernels (tiny) ----------------
__global__ void k_affine(const float* __restrict__ g1, const float* __restrict__ b1,
                         const float* __restrict__ m1, const float* __restrict__ v1,
                         const float* __restrict__ g2, const float* __restrict__ b2,
                         const float* __restrict__ m2, const float* __restrict__ v2,
                         float* __restrict__ ws) {
    for (int idx = threadIdx.x; idx < 2 * D1; idx += blockDim.x) {
        if (idx < D1) {
            float a = g1[idx] * rsqrtf(v1[idx] + EPS);
            ws[OFF_A1 + idx] = a;
            ws[OFF_C1 + idx] = b1[idx] - m1[idx] * a;
        } else {
            int n = idx - D1;
            float a = g2[n] * rsqrtf(v2[n] + EPS);
            ws[OFF_A2 + n] = a;
            ws[OFF_C2 + n] = b2[n] - m2[n] * a;
        }
    }
}

__global__ void k_weff(const float* __restrict__ W1, const float* __restrict__ W2,
                       float* __restrict__ ws) {
    int idx = blockIdx.x * blockDim.x + threadIdx.x;
    if (idx >= 384 * D1 + D1) return;
    const float* a1 = ws + OFF_A1;
    const float* c1 = ws + OFF_C1;
    const float* a2 = ws + OFF_A2;
    const float* c2 = ws + OFF_C2;
    if (idx < 384 * D1) {
        int k = idx / D1, n = idx % D1;
        float s = 0.f;
        for (int t = 0; t < D1; ++t)
            s += W1[(size_t)k * D1 + t] * a1[t] * W2[(size_t)t * D1 + n];
        ws[OFF_WEFF + idx] = s * a2[n];
    } else {
        int n = idx - 384 * D1;
        float s = 0.f;
        for (int t = 0; t < D1; ++t)
            s += c1[t] * W2[(size_t)t * D1 + n];
        ws[OFF_DVEC + n] = s * a2[n] + c2[n];
    }
}

__global__ void k_resid(const float* __restrict__ r1w1, const float* __restrict__ r1b1,
                        const float* __restrict__ r1w2, const float* __restrict__ r1b2,
                        const float* __restrict__ r2w1, const float* __restrict__ r2b1,
                        const float* __restrict__ r2w2, const float* __restrict__ r2b2,
                        float* __restrict__ ws) {
    int idx = blockIdx.x * blockDim.x + threadIdx.x;
    if (idx >= 2 * (128 * 128 + 128)) return;
    int layer = idx / (128 * 128 + 128);
    int r = idx % (128 * 128 + 128);
    const float* w1 = layer ? r2w1 : r1w1;
    const float* b1 = layer ? r2b1 : r1b1;
    const float* w2 = layer ? r2w2 : r1w2;
    const float* b2 = layer ? r2b2 : r1b2;
    float* Q = ws + (layer ? OFF_Q2 : OFF_Q1);
    float* q = ws + (layer ? OFF_q2 : OFF_q1);
    if (r < 128 * 128) {
        int i = r >> 7, j = r & 127;
        float s = (i == j) ? 1.f : 0.f;
        for (int t = 0; t < 128; ++t)
            s += w1[i * 128 + t] * w2[t * 128 + j];
        Q[r] = s;
    } else {
        int j = r - 128 * 128;
        float s = b2[j];
        for (int t = 0; t < 128; ++t)
            s += b1[t] * w2[t * 128 + j];
        q[j] = s;
    }
}

__global__ void k_qf(float* __restrict__ ws) {
    int idx = blockIdx.x * blockDim.x + threadIdx.x;
    if (idx >= 128 * 128 + 128) return;
    const float* Q1 = ws + OFF_Q1;
    const float* Q2 = ws + OFF_Q2;
    if (idx < 128 * 128) {
        int i = idx >> 7, j = idx & 127;
        float s = 0.f;
        for (int m = 0; m < 128; ++m)
            s += Q1[i * 128 + m] * Q2[m * 128 + j];
        ws[OFF_QF + idx] = s;
    } else {
        int j = idx - 128 * 128;
        const float* q1 = ws + OFF_q1;
        float s = ws[OFF_q2 + j];
        for (int m = 0; m < 128; ++m)
            s += q1[m] * Q2[m * 128 + j];
        ws[OFF_qf + j] = s;
    }
}

// pack transposed bf16 weights: WmidT/WtopT/WbotT [144][128], QfT [128][128]
__global__ void k_pack(float* __restrict__ ws) {
    int idx = blockIdx.x * blockDim.x + threadIdx.x;
    const float* Weff = ws + OFF_WEFF;
    if (idx < 18432) {
        int n = idx >> 7, k = idx & 127;
        float v = (n < 128) ? Weff[(size_t)(128 + k) * D1 + n + 1]
                            : ((n == 128) ? Weff[(size_t)(128 + k) * D1] : 0.f);
        ((bf16_t*)(ws + OFF_WMT))[idx] = (bf16_t)v;
    } else if (idx < 2 * 18432) {
        int r = idx - 18432;
        int n = r >> 7, k = r & 127;
        float v = (n < D1) ? Weff[(size_t)k * D1 + n] : 0.f;
        ((bf16_t*)(ws + OFF_WTT))[r] = (bf16_t)v;
    } else if (idx < 3 * 18432) {
        int r = idx - 2 * 18432;
        int n = r >> 7, k = r & 127;
        float v = (n < D1) ? Weff[(size_t)(256 + k) * D1 + n] : 0.f;
        ((bf16_t*)(ws + OFF_WBT))[r] = (bf16_t)v;
    } else if (idx < 3 * 18432 + 16384) {
        int r = idx - 3 * 18432;
        int n = r >> 7, k = r & 127;
        ((bf16_t*)(ws + OFF_QFT))[r] = (bf16_t)ws[OFF_QF + k * 128 + n];
    }
}

// ---------------- CSR build: histogram -> parallel scan -> scatter ----------------
__global__ void k_hist(const int* __restrict__ idx_i, float* __restrict__ ws) {
    int e = blockIdx.x * blockDim.x + threadIdx.x;
    if (e < NE) atomicAdd((int*)(ws + OFF_CNT) + idx_i[e], 1);
}

__global__ void k_scan1(float* __restrict__ ws) {
    const int* cnt = (const int*)(ws + OFF_CNT);
    int i = blockIdx.x * 256 + threadIdx.x;
    int v = (i < NA) ? cnt[i] : 0;
#pragma unroll
    for (int o = 1; o < 64; o <<= 1) v += __shfl_xor(v, o);
    __shared__ int wsum[4];
    if ((threadIdx.x & 63) == 0) wsum[threadIdx.x >> 6] = v;
    __syncthreads();
    if (threadIdx.x == 0)
        ((int*)(ws + OFF_PART))[blockIdx.x] = wsum[0] + wsum[1] + wsum[2] + wsum[3];
}

__global__ void k_scan2(float* __restrict__ ws) {
    int* part = (int*)(ws + OFF_PART);
    __shared__ int ps[256];
    int t = threadIdx.x;
    int v = (t < SCAN_NB) ? part[t] : 0;
    ps[t] = v;
    __syncthreads();
    for (int o = 1; o < 256; o <<= 1) {
        int u = (t >= o) ? ps[t - o] : 0;
        __syncthreads();
        ps[t] += u;
        __syncthreads();
    }
    part[t] = t ? ps[t - 1] : 0;  // exclusive base per block
}

__global__ void k_scan3(float* __restrict__ ws) {
    const int* cnt = (const int*)(ws + OFF_CNT);
    int* cursor = (int*)(ws + OFF_CUR);
    int base = ((const int*)(ws + OFF_PART))[blockIdx.x];
    int i = blockIdx.x * 256 + threadIdx.x;
    int v = (i < NA) ? cnt[i] : 0;
    int lane = threadIdx.x & 63, w = threadIdx.x >> 6;
    int s = v;
#pragma unroll
    for (int o = 1; o < 64; o <<= 1) {
        int u = __shfl_up(s, o);
        if (lane >= o) s += u;
    }
    __shared__ int wtot[4];
    if (lane == 63) wtot[w] = s;
    __syncthreads();
    int add = 0;
    for (int k = 0; k < 4; ++k)
        if (k < w) add += wtot[k];
    if (i < NA) cursor[i] = base + add + s - v;  // exclusive prefix
}

__global__ void k_scatter(const int* __restrict__ idx_i, float* __restrict__ ws) {
    int e = blockIdx.x * blockDim.x + threadIdx.x;
    if (e < NE) {
        int i = idx_i[e];
        int p = atomicAdd((int*)(ws + OFF_CUR) + i, 1);
        ((int*)(ws + OFF_EDG))[p] = e;
    }
}

// ---------------- MFMA dense GEMM: C[M][N] = (A + A2 + acc2*Pi') @ Wt^T + bias ----------------
__global__ __launch_bounds__(256) void k_gemm_mfma(
    const float* __restrict__ A, const float* __restrict__ A2,
    const float* __restrict__ Pi, const float* __restrict__ acc2,
    const bf16_t* __restrict__ Wt, const float* __restrict__ bias,
    float* __restrict__ C, int ldc, int N, int ntiles, int M) {
    __shared__ __align__(16) bf16_t As[64][136];
    int t = threadIdx.x;
    int m0 = blockIdx.x * 64;
#pragma unroll
    for (int it = 0; it < 8; ++it) {
        int idx = t + 256 * it;
        int r = idx >> 5, c4 = idx & 31;
        int grow = m0 + r;
        float4 v = make_float4(0.f, 0.f, 0.f, 0.f);
        if (grow < M) {
            v = ((const float4*)(A + (size_t)grow * 128))[c4];
            if (A2) {
                float4 w = ((const float4*)(A2 + (size_t)grow * 128))[c4];
                v.x += w.x; v.y += w.y; v.z += w.z; v.w += w.w;
            }
            if (acc2) {
                float s = acc2[grow];
                const float* p = Pi + (size_t)grow * D1 + 1 + c4 * 4;
                v.x += s * p[0]; v.y += s * p[1]; v.z += s * p[2]; v.w += s * p[3];
            }
        }
        bf16x4 tmp;
        tmp[0] = (bf16_t)v.x; tmp[1] = (bf16_t)v.y; tmp[2] = (bf16_t)v.z; tmp[3] = (bf16_t)v.w;
        *(bf16x4*)&As[r][c4 * 4] = tmp;
    }
    __syncthreads();
    int lane = t & 63, w = t >> 6;
    int ll = lane & 15, quad = lane >> 4;
    bf16x8 a[4];
#pragma unroll
    for (int k = 0; k < 4; ++k)
        a[k] = *(const bf16x8*)&As[w * 16 + ll][k * 32 + quad * 8];
    for (int nt = 0; nt < ntiles; ++nt) {
        const bf16_t* bp = Wt + (size_t)(nt * 16 + ll) * 128 + quad * 8;
        f32x4 acc = {0.f, 0.f, 0.f, 0.f};
#pragma unroll
        for (int k = 0; k < 4; ++k) {
            bf16x8 b = *(const bf16x8*)(bp + k * 32);
            acc = __builtin_amdgcn_mfma_f32_16x16x32_bf16(a[k], b, acc, 0, 0, 0);
        }
        int col = nt * 16 + ll;
        if (col < N) {
            float bv = bias ? bias[col] : 0.f;
#pragma unroll
            for (int r = 0; r < 4; ++r) {
                int row = m0 + w * 16 + quad * 4 + r;
                if (row < M) C[(size_t)row * ldc + col] = acc[r] + bv;
            }
        }
    }
}

// ---------------- fused Pi/Pj GEMM: stage A once, two weight sets ----------------
__global__ __launch_bounds__(256) void k_pipj(
    const float* __restrict__ A, const bf16_t* __restrict__ Wt,
    const float* __restrict__ bias, float* __restrict__ Ct,
    const bf16_t* __restrict__ Wb, float* __restrict__ Cb, int M) {
    __shared__ __align__(16) bf16_t As[64][136];
    int t = threadIdx.x;
    int m0 = blockIdx.x * 64;
#pragma unroll
    for (int it = 0; it < 8; ++it) {
        int idx = t + 256 * it;
        int r = idx >> 5, c4 = idx & 31;
        int grow = m0 + r;
        float4 v = make_float4(0.f, 0.f, 0.f, 0.f);
        if (grow < M) v = ((const float4*)(A + (size_t)grow * 128))[c4];
        bf16x4 tmp;
        tmp[0] = (bf16_t)v.x; tmp[1] = (bf16_t)v.y; tmp[2] = (bf16_t)v.z; tmp[3] = (bf16_t)v.w;
        *(bf16x4*)&As[r][c4 * 4] = tmp;
    }
    __syncthreads();
    int lane = t & 63, w = t >> 6;
    int ll = lane & 15, quad = lane >> 4;
    bf16x8 a[4];
#pragma unroll
    for (int k = 0; k < 4; ++k)
        a[k] = *(const bf16x8*)&As[w * 16 + ll][k * 32 + quad * 8];
    for (int half = 0; half < 2; ++half) {
        const bf16_t* W = half ? Wb : Wt;
        float* C = half ? Cb : Ct;
        for (int nt = 0; nt < 9; ++nt) {
            const bf16_t* bp = W + (size_t)(nt * 16 + ll) * 128 + quad * 8;
            f32x4 acc = {0.f, 0.f, 0.f, 0.f};
#pragma unroll
            for (int k = 0; k < 4; ++k) {
                bf16x8 b = *(const bf16x8*)(bp + k * 32);
                acc = __builtin_amdgcn_mfma_f32_16x16x32_bf16(a[k], b, acc, 0, 0, 0);
            }
            int col = nt * 16 + ll;
            if (col < D1) {
                float bv = (half == 0 && bias) ? bias[col] : 0.f;
#pragma unroll
                for (int r = 0; r < 4; ++r) {
                    int row = m0 + w * 16 + quad * 4 + r;
                    if (row < M) C[(size_t)row * D1 + col] = acc[r] + bv;
                }
            }
        }
    }
}

// ---------------- edge kernel (destination-sorted): y2 = bond@Wmid + Pi[i] + Pj[j];
// msg = y2[0]*y2[1:]; in-REGISTER per-wave segmented reduction -> coalesced atomics ----------------
__global__ __launch_bounds__(256) void k_edge_mfma(
    const float* __restrict__ bond, const int* __restrict__ idx_i,
    const int* __restrict__ idx_j, const int* __restrict__ edge_of,
    const bf16_t* __restrict__ WmidT,
    const float* __restrict__ Pi, const float* __restrict__ Pj,
    float* __restrict__ accb, float* __restrict__ acc2) {
    __shared__ __align__(16) bf16_t As[64][136];
    __shared__ int e_s[64], ii_s[64], jj_s[64];

    int t = threadIdx.x;
    size_t p0 = (size_t)blockIdx.x * 64;
    if (t < 64) {
        int e = edge_of[p0 + t];
        e_s[t] = e;
        ii_s[t] = idx_i[e];
        jj_s[t] = idx_j[e];
    }
    __syncthreads();
#pragma unroll
    for (int it = 0; it < 8; ++it) {
        int idx = t + 256 * it;
        int r = idx >> 5, c4 = idx & 31;
        float4 v = ((const float4*)(bond + (size_t)e_s[r] * 128))[c4];
        bf16x4 tmp;
        tmp[0] = (bf16_t)v.x; tmp[1] = (bf16_t)v.y; tmp[2] = (bf16_t)v.z; tmp[3] = (bf16_t)v.w;
        *(bf16x4*)&As[r][c4 * 4] = tmp;
    }
    __syncthreads();
    int lane = t & 63, w = t >> 6;
    int ll = lane & 15, quad = lane >> 4;
    bf16x8 a[4];
#pragma unroll
    for (int k = 0; k < 4; ++k)
        a[k] = *(const bf16x8*)&As[w * 16 + ll][k * 32 + quad * 8];

    int base = w * 16;
    // wave-uniform run mask over the wave's 16 sorted edges
    int my = ii_s[base + ll];
    int pv = ll ? ii_s[base + ll - 1] : my;
    unsigned runmask = (unsigned)(__ballot(lane < 16 && my != pv) & 0xFFFFull);

    // per-acc-reg byte offsets into Pj (element 1 of row j)
    int jo[4];
#pragma unroll
    for (int r = 0; r < 4; ++r) {
        int e = base + quad * 4 + r;
        jo[r] = jj_s[e] * (D1 * 4) + 4;
    }

    // gate tile (WmidT rows 128..143; row 128 = gate column, rest zero)
    f32x4 ag = {0.f, 0.f, 0.f, 0.f};
    {
        const bf16_t* bp = WmidT + (size_t)(128 + ll) * 128 + quad * 8;
#pragma unroll
        for (int k = 0; k < 4; ++k) {
            bf16x8 b = *(const bf16x8*)(bp + k * 32);
            ag = __builtin_amdgcn_mfma_f32_16x16x32_bf16(a[k], b, ag, 0, 0, 0);
        }
    }
    float g[4];
    int src = lane & 48;  // lane quad*16 holds the gate (col 0 of the tile)
#pragma unroll
    for (int r = 0; r < 4; ++r) {
        float v = ag[r];
        if (ll == 0) {
            int e = base + quad * 4 + r;
            v += Pi[(size_t)ii_s[e] * D1] + Pj[(size_t)jj_s[e] * D1];
        }
        g[r] = __shfl(v, src);
    }

    // gate scatter: per-run register reduce, one atomic per run
    {
        int rs = 0;
        while (rs < 16) {
            unsigned rest = runmask >> (rs + 1);
            int re = rest ? rs + 1 + __builtin_ctz(rest) : 16;
            float s = 0.f;
#pragma unroll
            for (int r = 0; r < 4; ++r) {
                int e = quad * 4 + r;
                if (e >= rs && e < re) s += g[r];
            }
            s += __shfl_xor(s, 16);
            s += __shfl_xor(s, 32);
            if (lane == 0) atomicAdd(&acc2[ii_s[base + rs]], s);
            rs = re;
        }
    }

    const char* Pjb = (const char*)Pj;
    for (int nt = 0; nt < 8; ++nt) {
        const bf16_t* bp = WmidT + (size_t)(nt * 16 + ll) * 128 + quad * 8;
        f32x4 acc = {0.f, 0.f, 0.f, 0.f};
#pragma unroll
        for (int k = 0; k < 4; ++k) {
            bf16x8 b = *(const bf16x8*)(bp + k * 32);
            acc = __builtin_amdgcn_mfma_f32_16x16x32_bf16(a[k], b, acc, 0, 0, 0);
        }
        int n = nt * 16 + ll;
        float m[4];
#pragma unroll
        for (int r = 0; r < 4; ++r) {
            float y = acc[r] + *(const float*)(Pjb + (size_t)jo[r] + n * 4);
            m[r] = g[r] * y;
        }
        // segmented per-run reduce across the wave's 16 edges, coalesced 64B atomic per run
        int rs = 0;
        while (rs < 16) {
            unsigned rest = runmask >> (rs + 1);
            int re = rest ? rs + 1 + __builtin_ctz(rest) : 16;
            float s = 0.f;
#pragma unroll
            for (int r = 0; r < 4; ++r) {
                int e = quad * 4 + r;
                if (e >= rs && e < re) s += m[r];
            }
            s += __shfl_xor(s, 16);
            s += __shfl_xor(s, 32);
            if (quad == 0) atomicAdd(&accb[(size_t)ii_s[base + rs] * 128 + n], s);
            rs = re;
        }
    }
}

extern "C" void kernel_launch(void* const* d_in, const int* in_sizes, int n_in,
                              void* d_out, int out_size, void* d_ws, size_t ws_size,
                              hipStream_t stream) {
    const float* atom = (const float*)d_in[0];
    const float* bond = (const float*)d_in[1];
    const int* idx_i = (const int*)d_in[2];
    const int* idx_j = (const int*)d_in[3];
    const float* W1 = (const float*)d_in[4];
    const float* g1 = (const float*)d_in[5];
    const float* b1 = (const float*)d_in[6];
    const float* m1 = (const float*)d_in[7];
    const float* v1 = (const float*)d_in[8];
    const float* W2 = (const float*)d_in[9];
    const float* g2 = (const float*)d_in[10];
    const float* b2 = (const float*)d_in[11];
    const float* m2 = (const float*)d_in[12];
    const float* v2 = (const float*)d_in[13];
    const float* r1w1 = (const float*)d_in[14];
    const float* r1b1 = (const float*)d_in[15];
    const float* r1w2 = (const float*)d_in[16];
    const float* r1b2 = (const float*)d_in[17];
    const float* r2w1 = (const float*)d_in[18];
    const float* r2b1 = (const float*)d_in[19];
    const float* r2w2 = (const float*)d_in[20];
    const float* r2b2 = (const float*)d_in[21];
    float* ws = (float*)d_ws;
    float* out = (float*)d_out;

    // zero ACC + ACC2 + CNT (contiguous) up front
    hipMemsetAsync(ws + OFF_ACC, 0, (size_t)(NA * HH + 2 * NA) * sizeof(float), stream);

    // CSR build (independent of weight prep)
    k_hist<<<(NE + 255) / 256, 256, 0, stream>>>(idx_i, ws);
    k_scan1<<<SCAN_NB, 256, 0, stream>>>(ws);
    k_scan2<<<1, 256, 0, stream>>>(ws);
    k_scan3<<<SCAN_NB, 256, 0, stream>>>(ws);
    k_scatter<<<(NE + 255) / 256, 256, 0, stream>>>(idx_i, ws);

    k_affine<<<1, 256, 0, stream>>>(g1, b1, m1, v1, g2, b2, m2, v2, ws);
    k_weff<<<(384 * D1 + D1 + 255) / 256, 256, 0, stream>>>(W1, W2, ws);
    k_resid<<<(2 * (128 * 128 + 128) + 255) / 256, 256, 0, stream>>>(
        r1w1, r1b1, r1w2, r1b2, r2w1, r2b1, r2w2, r2b2, ws);
    k_qf<<<(128 * 128 + 128 + 255) / 256, 256, 0, stream>>>(ws);
    k_pack<<<(3 * 18432 + 16384 + 255) / 256, 256, 0, stream>>>(ws);

    // Pi = atom @ Wtop + dvec ; Pj = atom @ Wbot   (N=129), fused: stage atom once
    int gblocks = (NA + 63) / 64;
    k_pipj<<<gblocks, 256, 0, stream>>>(
        atom, (const bf16_t*)(ws + OFF_WTT), ws + OFF_DVEC, ws + OFF_PI,
        (const bf16_t*)(ws + OFF_WBT), ws + OFF_PJ, NA);

    k_edge_mfma<<<NE / 64, 256, 0, stream>>>(
        bond, idx_i, idx_j, (const int*)(ws + OFF_EDG), (const bf16_t*)(ws + OFF_WMT),
        ws + OFF_PI, ws + OFF_PJ, ws + OFF_ACC, ws + OFF_ACC2);

    // out = (atom + acc + acc2*Pi') @ Qf + qf
    k_gemm_mfma<<<gblocks, 256, 0, stream>>>(
        atom, ws + OFF_ACC, ws + OFF_PI, ws + OFF_ACC2, (const bf16_t*)(ws + OFF_QFT),
        ws + OFF_qf, out, 128, 128, 8, NA);
}

// Round 3
// 1645.326 us; speedup vs baseline: 1.4644x; 1.1127x over previous
//
#include <hip/hip_runtime.h>

#define NA 50000
#define NE 1600000
#define HH 128
#define D1 129
#define EPS 1e-3f

typedef __bf16 bf16_t;
typedef bf16_t bf16x8 __attribute__((ext_vector_type(8)));
typedef bf16_t bf16x4 __attribute__((ext_vector_type(4)));
typedef float f32x4 __attribute__((ext_vector_type(4)));

// ---- workspace layout (float offsets) ----
#define OFF_A1   0
#define OFF_C1   129
#define OFF_A2   258
#define OFF_C2   387
#define OFF_WEFF 516
#define OFF_DVEC (OFF_WEFF + 384*129)          // 50052
#define OFF_Q1   (OFF_DVEC + 129)              // 50181
#define OFF_Q2   (OFF_Q1 + 128*128)
#define OFF_q1   (OFF_Q2 + 128*128)
#define OFF_q2   (OFF_q1 + 128)
#define OFF_QF   (OFF_q2 + 128)
#define OFF_qf   (OFF_QF + 128*128)
#define OFF_WMT  (((OFF_qf + 128) + 3) & ~3)   // WmidT bf16 [144][128] -> 9216 floats
#define OFF_WTT  (OFF_WMT + 9216)              // WtopT bf16 [144][128]
#define OFF_WBT  (OFF_WTT + 9216)              // WbotT bf16 [144][128]
#define OFF_QFT  (OFF_WBT + 9216)              // QfT  bf16 [128][128] -> 8192 floats
#define OFF_PI   (OFF_QFT + 8192)
#define OFF_PJ   (OFF_PI + NA*D1)
#define OFF_ACC  (OFF_PJ + NA*D1)
#define OFF_ACC2 (OFF_ACC + NA*HH)
// CSR scratch (ints stored in float slots)
#define OFF_CNT  (OFF_ACC2 + NA)               // int cnt[NA]   (zeroed by the big memset)
#define OFF_CUR  (OFF_CNT + NA)                // int cursor[NA]
#define OFF_EDG  (OFF_CUR + NA)                // int edge_of[NE]
#define OFF_PART (OFF_EDG + NE)                // int partial sums for scan (256)
#define SCAN_NB  ((NA + 255) / 256)            // 196

// ---------------- setup kernels (tiny) ----------------
__global__ void k_affine(const float* __restrict__ g1, const float* __restrict__ b1,
                         const float* __restrict__ m1, const float* __restrict__ v1,
                         const float* __restrict__ g2, const float* __restrict__ b2,
                         const float* __restrict__ m2, const float* __restrict__ v2,
                         float* __restrict__ ws) {
    for (int idx = threadIdx.x; idx < 2 * D1; idx += blockDim.x) {
        if (idx < D1) {
            float a = g1[idx] * rsqrtf(v1[idx] + EPS);
            ws[OFF_A1 + idx] = a;
            ws[OFF_C1 + idx] = b1[idx] - m1[idx] * a;
        } else {
            int n = idx - D1;
            float a = g2[n] * rsqrtf(v2[n] + EPS);
            ws[OFF_A2 + n] = a;
            ws[OFF_C2 + n] = b2[n] - m2[n] * a;
        }
    }
}

__global__ void k_weff(const float* __restrict__ W1, const float* __restrict__ W2,
                       float* __restrict__ ws) {
    int idx = blockIdx.x * blockDim.x + threadIdx.x;
    if (idx >= 384 * D1 + D1) return;
    const float* a1 = ws + OFF_A1;
    const float* c1 = ws + OFF_C1;
    const float* a2 = ws + OFF_A2;
    const float* c2 = ws + OFF_C2;
    if (idx < 384 * D1) {
        int k = idx / D1, n = idx % D1;
        float s = 0.f;
        for (int t = 0; t < D1; ++t)
            s += W1[(size_t)k * D1 + t] * a1[t] * W2[(size_t)t * D1 + n];
        ws[OFF_WEFF + idx] = s * a2[n];
    } else {
        int n = idx - 384 * D1;
        float s = 0.f;
        for (int t = 0; t < D1; ++t)
            s += c1[t] * W2[(size_t)t * D1 + n];
        ws[OFF_DVEC + n] = s * a2[n] + c2[n];
    }
}

__global__ void k_resid(const float* __restrict__ r1w1, const float* __restrict__ r1b1,
                        const float* __restrict__ r1w2, const float* __restrict__ r1b2,
                        const float* __restrict__ r2w1, const float* __restrict__ r2b1,
                        const float* __restrict__ r2w2, const float* __restrict__ r2b2,
                        float* __restrict__ ws) {
    int idx = blockIdx.x * blockDim.x + threadIdx.x;
    if (idx >= 2 * (128 * 128 + 128)) return;
    int layer = idx / (128 * 128 + 128);
    int r = idx % (128 * 128 + 128);
    const float* w1 = layer ? r2w1 : r1w1;
    const float* b1 = layer ? r2b1 : r1b1;
    const float* w2 = layer ? r2w2 : r1w2;
    const float* b2 = layer ? r2b2 : r1b2;
    float* Q = ws + (layer ? OFF_Q2 : OFF_Q1);
    float* q = ws + (layer ? OFF_q2 : OFF_q1);
    if (r < 128 * 128) {
        int i = r >> 7, j = r & 127;
        float s = (i == j) ? 1.f : 0.f;
        for (int t = 0; t < 128; ++t)
            s += w1[i * 128 + t] * w2[t * 128 + j];
        Q[r] = s;
    } else {
        int j = r - 128 * 128;
        float s = b2[j];
        for (int t = 0; t < 128; ++t)
            s += b1[t] * w2[t * 128 + j];
        q[j] = s;
    }
}

__global__ void k_qf(float* __restrict__ ws) {
    int idx = blockIdx.x * blockDim.x + threadIdx.x;
    if (idx >= 128 * 128 + 128) return;
    const float* Q1 = ws + OFF_Q1;
    const float* Q2 = ws + OFF_Q2;
    if (idx < 128 * 128) {
        int i = idx >> 7, j = idx & 127;
        float s = 0.f;
        for (int m = 0; m < 128; ++m)
            s += Q1[i * 128 + m] * Q2[m * 128 + j];
        ws[OFF_QF + idx] = s;
    } else {
        int j = idx - 128 * 128;
        const float* q1 = ws + OFF_q1;
        float s = ws[OFF_q2 + j];
        for (int m = 0; m < 128; ++m)
            s += q1[m] * Q2[m * 128 + j];
        ws[OFF_qf + j] = s;
    }
}

// pack transposed bf16 weights: WmidT/WtopT/WbotT [144][128], QfT [128][128]
__global__ void k_pack(float* __restrict__ ws) {
    int idx = blockIdx.x * blockDim.x + threadIdx.x;
    const float* Weff = ws + OFF_WEFF;
    if (idx < 18432) {
        int n = idx >> 7, k = idx & 127;
        float v = (n < 128) ? Weff[(size_t)(128 + k) * D1 + n + 1]
                            : ((n == 128) ? Weff[(size_t)(128 + k) * D1] : 0.f);
        ((bf16_t*)(ws + OFF_WMT))[idx] = (bf16_t)v;
    } else if (idx < 2 * 18432) {
        int r = idx - 18432;
        int n = r >> 7, k = r & 127;
        float v = (n < D1) ? Weff[(size_t)k * D1 + n] : 0.f;
        ((bf16_t*)(ws + OFF_WTT))[r] = (bf16_t)v;
    } else if (idx < 3 * 18432) {
        int r = idx - 2 * 18432;
        int n = r >> 7, k = r & 127;
        float v = (n < D1) ? Weff[(size_t)(256 + k) * D1 + n] : 0.f;
        ((bf16_t*)(ws + OFF_WBT))[r] = (bf16_t)v;
    } else if (idx < 3 * 18432 + 16384) {
        int r = idx - 3 * 18432;
        int n = r >> 7, k = r & 127;
        ((bf16_t*)(ws + OFF_QFT))[r] = (bf16_t)ws[OFF_QF + k * 128 + n];
    }
}

// ---------------- CSR build: histogram -> parallel scan -> scatter ----------------
__global__ void k_hist(const int* __restrict__ idx_i, float* __restrict__ ws) {
    int e = blockIdx.x * blockDim.x + threadIdx.x;
    if (e < NE) atomicAdd((int*)(ws + OFF_CNT) + idx_i[e], 1);
}

__global__ void k_scan1(float* __restrict__ ws) {
    const int* cnt = (const int*)(ws + OFF_CNT);
    int i = blockIdx.x * 256 + threadIdx.x;
    int v = (i < NA) ? cnt[i] : 0;
#pragma unroll
    for (int o = 1; o < 64; o <<= 1) v += __shfl_xor(v, o);
    __shared__ int wsum[4];
    if ((threadIdx.x & 63) == 0) wsum[threadIdx.x >> 6] = v;
    __syncthreads();
    if (threadIdx.x == 0)
        ((int*)(ws + OFF_PART))[blockIdx.x] = wsum[0] + wsum[1] + wsum[2] + wsum[3];
}

__global__ void k_scan2(float* __restrict__ ws) {
    int* part = (int*)(ws + OFF_PART);
    __shared__ int ps[256];
    int t = threadIdx.x;
    int v = (t < SCAN_NB) ? part[t] : 0;
    ps[t] = v;
    __syncthreads();
    for (int o = 1; o < 256; o <<= 1) {
        int u = (t >= o) ? ps[t - o] : 0;
        __syncthreads();
        ps[t] += u;
        __syncthreads();
    }
    part[t] = t ? ps[t - 1] : 0;  // exclusive base per block
}

__global__ void k_scan3(float* __restrict__ ws) {
    const int* cnt = (const int*)(ws + OFF_CNT);
    int* cursor = (int*)(ws + OFF_CUR);
    int base = ((const int*)(ws + OFF_PART))[blockIdx.x];
    int i = blockIdx.x * 256 + threadIdx.x;
    int v = (i < NA) ? cnt[i] : 0;
    int lane = threadIdx.x & 63, w = threadIdx.x >> 6;
    int s = v;
#pragma unroll
    for (int o = 1; o < 64; o <<= 1) {
        int u = __shfl_up(s, o);
        if (lane >= o) s += u;
    }
    __shared__ int wtot[4];
    if (lane == 63) wtot[w] = s;
    __syncthreads();
    int add = 0;
    for (int k = 0; k < 4; ++k)
        if (k < w) add += wtot[k];
    if (i < NA) cursor[i] = base + add + s - v;  // exclusive prefix
}

__global__ void k_scatter(const int* __restrict__ idx_i, float* __restrict__ ws) {
    int e = blockIdx.x * blockDim.x + threadIdx.x;
    if (e < NE) {
        int i = idx_i[e];
        int p = atomicAdd((int*)(ws + OFF_CUR) + i, 1);
        ((int*)(ws + OFF_EDG))[p] = e;
    }
}

// ---------------- MFMA dense GEMM: C[M][N] = (A + A2 + acc2*Pi') @ Wt^T + bias ----------------
__global__ __launch_bounds__(256) void k_gemm_mfma(
    const float* __restrict__ A, const float* __restrict__ A2,
    const float* __restrict__ Pi, const float* __restrict__ acc2,
    const bf16_t* __restrict__ Wt, const float* __restrict__ bias,
    float* __restrict__ C, int ldc, int N, int ntiles, int M) {
    __shared__ __align__(16) bf16_t As[64][136];
    int t = threadIdx.x;
    int m0 = blockIdx.x * 64;
#pragma unroll
    for (int it = 0; it < 8; ++it) {
        int idx = t + 256 * it;
        int r = idx >> 5, c4 = idx & 31;
        int grow = m0 + r;
        float4 v = make_float4(0.f, 0.f, 0.f, 0.f);
        if (grow < M) {
            v = ((const float4*)(A + (size_t)grow * 128))[c4];
            if (A2) {
                float4 w = ((const float4*)(A2 + (size_t)grow * 128))[c4];
                v.x += w.x; v.y += w.y; v.z += w.z; v.w += w.w;
            }
            if (acc2) {
                float s = acc2[grow];
                const float* p = Pi + (size_t)grow * D1 + 1 + c4 * 4;
                v.x += s * p[0]; v.y += s * p[1]; v.z += s * p[2]; v.w += s * p[3];
            }
        }
        bf16x4 tmp;
        tmp[0] = (bf16_t)v.x; tmp[1] = (bf16_t)v.y; tmp[2] = (bf16_t)v.z; tmp[3] = (bf16_t)v.w;
        *(bf16x4*)&As[r][c4 * 4] = tmp;
    }
    __syncthreads();
    int lane = t & 63, w = t >> 6;
    int ll = lane & 15, quad = lane >> 4;
    bf16x8 a[4];
#pragma unroll
    for (int k = 0; k < 4; ++k)
        a[k] = *(const bf16x8*)&As[w * 16 + ll][k * 32 + quad * 8];
    for (int nt = 0; nt < ntiles; ++nt) {
        const bf16_t* bp = Wt + (size_t)(nt * 16 + ll) * 128 + quad * 8;
        f32x4 acc = {0.f, 0.f, 0.f, 0.f};
#pragma unroll
        for (int k = 0; k < 4; ++k) {
            bf16x8 b = *(const bf16x8*)(bp + k * 32);
            acc = __builtin_amdgcn_mfma_f32_16x16x32_bf16(a[k], b, acc, 0, 0, 0);
        }
        int col = nt * 16 + ll;
        if (col < N) {
            float bv = bias ? bias[col] : 0.f;
#pragma unroll
            for (int r = 0; r < 4; ++r) {
                int row = m0 + w * 16 + quad * 4 + r;
                if (row < M) C[(size_t)row * ldc + col] = acc[r] + bv;
            }
        }
    }
}

// ---------------- fused Pi/Pj GEMM: stage A once, two weight sets ----------------
__global__ __launch_bounds__(256) void k_pipj(
    const float* __restrict__ A, const bf16_t* __restrict__ Wt,
    const float* __restrict__ bias, float* __restrict__ Ct,
    const bf16_t* __restrict__ Wb, float* __restrict__ Cb, int M) {
    __shared__ __align__(16) bf16_t As[64][136];
    int t = threadIdx.x;
    int m0 = blockIdx.x * 64;
#pragma unroll
    for (int it = 0; it < 8; ++it) {
        int idx = t + 256 * it;
        int r = idx >> 5, c4 = idx & 31;
        int grow = m0 + r;
        float4 v = make_float4(0.f, 0.f, 0.f, 0.f);
        if (grow < M) v = ((const float4*)(A + (size_t)grow * 128))[c4];
        bf16x4 tmp;
        tmp[0] = (bf16_t)v.x; tmp[1] = (bf16_t)v.y; tmp[2] = (bf16_t)v.z; tmp[3] = (bf16_t)v.w;
        *(bf16x4*)&As[r][c4 * 4] = tmp;
    }
    __syncthreads();
    int lane = t & 63, w = t >> 6;
    int ll = lane & 15, quad = lane >> 4;
    bf16x8 a[4];
#pragma unroll
    for (int k = 0; k < 4; ++k)
        a[k] = *(const bf16x8*)&As[w * 16 + ll][k * 32 + quad * 8];
    for (int half = 0; half < 2; ++half) {
        const bf16_t* W = half ? Wb : Wt;
        float* C = half ? Cb : Ct;
        for (int nt = 0; nt < 9; ++nt) {
            const bf16_t* bp = W + (size_t)(nt * 16 + ll) * 128 + quad * 8;
            f32x4 acc = {0.f, 0.f, 0.f, 0.f};
#pragma unroll
            for (int k = 0; k < 4; ++k) {
                bf16x8 b = *(const bf16x8*)(bp + k * 32);
                acc = __builtin_amdgcn_mfma_f32_16x16x32_bf16(a[k], b, acc, 0, 0, 0);
            }
            int col = nt * 16 + ll;
            if (col < D1) {
                float bv = (half == 0 && bias) ? bias[col] : 0.f;
#pragma unroll
                for (int r = 0; r < 4; ++r) {
                    int row = m0 + w * 16 + quad * 4 + r;
                    if (row < M) C[(size_t)row * D1 + col] = acc[r] + bv;
                }
            }
        }
    }
}

// ---------------- edge kernel v3: B in swizzled LDS (once per block), 4 edge-tiles per
// block, double-buffered As, async-stage split, deferred atomics ----------------
__global__ __launch_bounds__(256) void k_edge_mfma(
    const float* __restrict__ bond, const int* __restrict__ idx_i,
    const int* __restrict__ idx_j, const int* __restrict__ edge_of,
    const bf16_t* __restrict__ WmidT,
    const float* __restrict__ Pi, const float* __restrict__ Pj,
    float* __restrict__ accb, float* __restrict__ acc2) {
    __shared__ __align__(16) bf16_t Bs[144 * 128];       // 36864 B, XOR-swizzled rows
    __shared__ __align__(16) bf16_t As[2][64][136];      // 34816 B
    __shared__ int e_all[256];
    __shared__ int ii2[2][64], jj2[2][64];

    int t = threadIdx.x;
    size_t p0 = (size_t)blockIdx.x * 256;
    e_all[t] = edge_of[p0 + t];

    // stage WmidT -> swizzled LDS (byte col ^= (row&7)<<4 within 256B rows)
    {
        const float4* src = (const float4*)WmidT;
#pragma unroll
        for (int k = 0; k < 9; ++k) {
            int idx16 = t + 256 * k;          // 2304 x 16B
            int g = idx16 << 4;               // byte offset
            int row = g >> 8;
            int swz = (g & 255) ^ ((row & 7) << 4);
            *(float4*)((char*)Bs + row * 256 + swz) = src[idx16];
        }
    }
    __syncthreads();

    // stage tile 0 (+ meta 0)
#pragma unroll
    for (int it = 0; it < 8; ++it) {
        int idx = t + 256 * it;
        int r = idx >> 5, c4 = idx & 31;
        float4 v = ((const float4*)(bond + (size_t)e_all[r] * 128))[c4];
        bf16x4 tmp;
        tmp[0] = (bf16_t)v.x; tmp[1] = (bf16_t)v.y; tmp[2] = (bf16_t)v.z; tmp[3] = (bf16_t)v.w;
        *(bf16x4*)&As[0][r][c4 * 4] = tmp;
    }
    if (t < 64) {
        int e = e_all[t];
        ii2[0][t] = idx_i[e];
        jj2[0][t] = idx_j[e];
    }
    __syncthreads();

    int lane = t & 63, w = t >> 6;
    int ll = lane & 15, quad = lane >> 4;
    int base = w * 16;
    int src_lane = lane & 48;

    for (int tt = 0; tt < 4; ++tt) {
        int buf = tt & 1;
        // a-frags for this tile
        bf16x8 a[4];
#pragma unroll
        for (int k = 0; k < 4; ++k)
            a[k] = *(const bf16x8*)&As[buf][base + ll][k * 32 + quad * 8];

        // meta for this tile
        int my = ii2[buf][base + ll];
        int pv = ll ? ii2[buf][base + ll - 1] : my;
        unsigned runmask = (unsigned)(__ballot(lane < 16 && my != pv) & 0xFFFFull);
        int jo[4];
#pragma unroll
        for (int r = 0; r < 4; ++r)
            jo[r] = jj2[buf][base + quad * 4 + r] * (D1 * 4) + 4;
        float gp[4] = {0.f, 0.f, 0.f, 0.f};
        if (ll == 0) {
#pragma unroll
            for (int r = 0; r < 4; ++r) {
                int e = base + quad * 4 + r;
                gp[r] = Pi[(size_t)ii2[buf][e] * D1] + Pj[(size_t)jj2[buf][e] * D1];
            }
        }

        // async-stage: issue next tile's loads now, write to LDS after compute
        float4 pf[8];
        int ni = 0, nj = 0;
        if (tt < 3) {
            int nb = (tt + 1) * 64;
#pragma unroll
            for (int it = 0; it < 8; ++it) {
                int idx = t + 256 * it;
                int r = idx >> 5, c4 = idx & 31;
                pf[it] = ((const float4*)(bond + (size_t)e_all[nb + r] * 128))[c4];
            }
            if (t < 64) {
                int e = e_all[nb + t];
                ni = idx_i[e];
                nj = idx_j[e];
            }
        }

        // gate tile (Bs rows 128..143)
        f32x4 ag = {0.f, 0.f, 0.f, 0.f};
#pragma unroll
        for (int k = 0; k < 4; ++k) {
            int row = 128 + ll;
            int colb = (quad * 16 + k * 64) ^ ((row & 7) << 4);
            bf16x8 b = *(const bf16x8*)((const char*)Bs + row * 256 + colb);
            ag = __builtin_amdgcn_mfma_f32_16x16x32_bf16(a[k], b, ag, 0, 0, 0);
        }
        float g[4];
#pragma unroll
        for (int r = 0; r < 4; ++r) {
            float v = ag[r];
            if (ll == 0) v += gp[r];
            g[r] = __shfl(v, src_lane);
        }

        // 8 n-tiles: MFMA from LDS B, Pj gather, message values into regs
        f32x4 mm[8];
#pragma unroll
        for (int nt = 0; nt < 8; ++nt) {
            float pjv[4];
#pragma unroll
            for (int r = 0; r < 4; ++r)
                pjv[r] = *(const float*)((const char*)Pj + (size_t)jo[r] + (nt * 16 + ll) * 4);
            f32x4 acc = {0.f, 0.f, 0.f, 0.f};
#pragma unroll
            for (int k = 0; k < 4; ++k) {
                int row = nt * 16 + ll;
                int colb = (quad * 16 + k * 64) ^ ((row & 7) << 4);
                bf16x8 b = *(const bf16x8*)((const char*)Bs + row * 256 + colb);
                acc = __builtin_amdgcn_mfma_f32_16x16x32_bf16(a[k], b, acc, 0, 0, 0);
            }
#pragma unroll
            for (int r = 0; r < 4; ++r) mm[nt][r] = g[r] * (acc[r] + pjv[r]);
        }

        // write back staged tile (pf loads have had the whole compute to land)
        if (tt < 3) {
            int nbuf = buf ^ 1;
#pragma unroll
            for (int it = 0; it < 8; ++it) {
                int idx = t + 256 * it;
                int r = idx >> 5, c4 = idx & 31;
                bf16x4 tmp;
                tmp[0] = (bf16_t)pf[it].x; tmp[1] = (bf16_t)pf[it].y;
                tmp[2] = (bf16_t)pf[it].z; tmp[3] = (bf16_t)pf[it].w;
                *(bf16x4*)&As[nbuf][r][c4 * 4] = tmp;
            }
            if (t < 64) {
                ii2[nbuf][t] = ni;
                jj2[nbuf][t] = nj;
            }
        }

        // deferred atomics: gate scatter
        {
            int rs = 0;
            while (rs < 16) {
                unsigned rest = runmask >> (rs + 1);
                int re = rest ? rs + 1 + __builtin_ctz(rest) : 16;
                float s = 0.f;
#pragma unroll
                for (int r = 0; r < 4; ++r) {
                    int e = quad * 4 + r;
                    if (e >= rs && e < re) s += g[r];
                }
                s += __shfl_xor(s, 16);
                s += __shfl_xor(s, 32);
                if (lane == 0) atomicAdd(&acc2[ii2[buf][base + rs]], s);
                rs = re;
            }
        }
        // deferred atomics: message scatter (per n-tile run reduce)
#pragma unroll
        for (int nt = 0; nt < 8; ++nt) {
            int n = nt * 16 + ll;
            int rs = 0;
            while (rs < 16) {
                unsigned rest = runmask >> (rs + 1);
                int re = rest ? rs + 1 + __builtin_ctz(rest) : 16;
                float s = 0.f;
#pragma unroll
                for (int r = 0; r < 4; ++r) {
                    int e = quad * 4 + r;
                    if (e >= rs && e < re) s += mm[nt][r];
                }
                s += __shfl_xor(s, 16);
                s += __shfl_xor(s, 32);
                if (quad == 0) atomicAdd(&accb[(size_t)ii2[buf][base + rs] * 128 + n], s);
                rs = re;
            }
        }
        __syncthreads();
    }
}

extern "C" void kernel_launch(void* const* d_in, const int* in_sizes, int n_in,
                              void* d_out, int out_size, void* d_ws, size_t ws_size,
                              hipStream_t stream) {
    const float* atom = (const float*)d_in[0];
    const float* bond = (const float*)d_in[1];
    const int* idx_i = (const int*)d_in[2];
    const int* idx_j = (const int*)d_in[3];
    const float* W1 = (const float*)d_in[4];
    const float* g1 = (const float*)d_in[5];
    const float* b1 = (const float*)d_in[6];
    const float* m1 = (const float*)d_in[7];
    const float* v1 = (const float*)d_in[8];
    const float* W2 = (const float*)d_in[9];
    const float* g2 = (const float*)d_in[10];
    const float* b2 = (const float*)d_in[11];
    const float* m2 = (const float*)d_in[12];
    const float* v2 = (const float*)d_in[13];
    const float* r1w1 = (const float*)d_in[14];
    const float* r1b1 = (const float*)d_in[15];
    const float* r1w2 = (const float*)d_in[16];
    const float* r1b2 = (const float*)d_in[17];
    const float* r2w1 = (const float*)d_in[18];
    const float* r2b1 = (const float*)d_in[19];
    const float* r2w2 = (const float*)d_in[20];
    const float* r2b2 = (const float*)d_in[21];
    float* ws = (float*)d_ws;
    float* out = (float*)d_out;

    // zero ACC + ACC2 + CNT (contiguous) up front
    hipMemsetAsync(ws + OFF_ACC, 0, (size_t)(NA * HH + 2 * NA) * sizeof(float), stream);

    // CSR build (independent of weight prep)
    k_hist<<<(NE + 255) / 256, 256, 0, stream>>>(idx_i, ws);
    k_scan1<<<SCAN_NB, 256, 0, stream>>>(ws);
    k_scan2<<<1, 256, 0, stream>>>(ws);
    k_scan3<<<SCAN_NB, 256, 0, stream>>>(ws);
    k_scatter<<<(NE + 255) / 256, 256, 0, stream>>>(idx_i, ws);

    k_affine<<<1, 256, 0, stream>>>(g1, b1, m1, v1, g2, b2, m2, v2, ws);
    k_weff<<<(384 * D1 + D1 + 255) / 256, 256, 0, stream>>>(W1, W2, ws);
    k_resid<<<(2 * (128 * 128 + 128) + 255) / 256, 256, 0, stream>>>(
        r1w1, r1b1, r1w2, r1b2, r2w1, r2b1, r2w2, r2b2, ws);
    k_qf<<<(128 * 128 + 128 + 255) / 256, 256, 0, stream>>>(ws);
    k_pack<<<(3 * 18432 + 16384 + 255) / 256, 256, 0, stream>>>(ws);

    // Pi = atom @ Wtop + dvec ; Pj = atom @ Wbot   (N=129), fused: stage atom once
    int gblocks = (NA + 63) / 64;
    k_pipj<<<gblocks, 256, 0, stream>>>(
        atom, (const bf16_t*)(ws + OFF_WTT), ws + OFF_DVEC, ws + OFF_PI,
        (const bf16_t*)(ws + OFF_WBT), ws + OFF_PJ, NA);

    k_edge_mfma<<<NE / 256, 256, 0, stream>>>(
        bond, idx_i, idx_j, (const int*)(ws + OFF_EDG), (const bf16_t*)(ws + OFF_WMT),
        ws + OFF_PI, ws + OFF_PJ, ws + OFF_ACC, ws + OFF_ACC2);

    // out = (atom + acc + acc2*Pi') @ Qf + qf
    k_gemm_mfma<<<gblocks, 256, 0, stream>>>(
        atom, ws + OFF_ACC, ws + OFF_PI, ws + OFF_ACC2, (const bf16_t*)(ws + OFF_QFT),
        ws + OFF_qf, out, 128, 128, 8, NA);
}